// Round 1
// baseline (1628.732 us; speedup 1.0000x reference)
//
#include <hip/hip_runtime.h>
#include <cmath>
#include <cstdint>

// Problem constants (from reference)
constexpr int B_ = 8, N_ = 1024, M_ = 512, D_ = 128, S_ = 1536, L_ = 6, DFF_ = 512;
constexpr int ROWS = B_ * S_;   // 12288
constexpr int MAXDEG = 64;      // max attention row degree (actual ~7-20)

// ---------------------------------------------------------------------------
// Setup: nodes = [|r_t| , syndrome], syndrome = (bits @ H^T) mod 2
// ---------------------------------------------------------------------------
__global__ void nodes_kernel(const float* __restrict__ r_t, const int* __restrict__ pcm,
                             float* __restrict__ nodes) {
  int idx = blockIdx.x * blockDim.x + threadIdx.x;
  if (idx >= B_ * S_) return;
  int b = idx / S_, s = idx % S_;
  if (s < N_) {
    nodes[idx] = fabsf(r_t[b * N_ + s]);
  } else {
    const int* row = pcm + (s - N_) * N_;
    const float* rb = r_t + b * N_;
    float sum = 0.f;
    for (int n = 0; n < N_; ++n) {
      if (row[n] != 0) {
        float r = rb[n];
        sum += (r < 0.f) ? 1.f : (r > 0.f ? 0.f : 0.5f);  // bits = 0.5*(1-sign)
      }
    }
    nodes[idx] = fmodf(sum, 2.0f);
  }
}

// te[b,d] = time_table[t[b], d]
__global__ void te_kernel(const int* __restrict__ t, const float* __restrict__ table,
                          float* __restrict__ te) {
  int idx = blockIdx.x * blockDim.x + threadIdx.x;
  if (idx >= B_ * D_) return;
  int b = idx / D_, d = idx % D_;
  te[idx] = table[t[b] * D_ + d];
}

// x[b,s,d] = te[b,d] * src_embed[s,d] * nodes[b,s]
__global__ void xinit_kernel(const float* __restrict__ nodes, const float* __restrict__ se,
                             const float* __restrict__ te, float* __restrict__ x) {
  int idx = blockIdx.x * blockDim.x + threadIdx.x;
  if (idx >= B_ * S_ * D_) return;
  int d = idx % D_;
  int bs = idx / D_;
  int b = bs / S_, s = bs % S_;
  x[idx] = te[b * D_ + d] * se[s * D_ + d] * nodes[bs];
}

// ---------------------------------------------------------------------------
// Adjacency from pcm: allowed(s,k) = (s==k) | Tanner edge. One wave per row,
// ballot-compacted, sorted. exp(-1e9-max) underflows to 0 in fp32, so sparse
// attention over this list is bit-equivalent to the dense masked softmax.
// ---------------------------------------------------------------------------
__global__ void adj_kernel(const int* __restrict__ pcm, int* __restrict__ adj,
                           int* __restrict__ adjcnt) {
  int s = blockIdx.x;
  int lane = threadIdx.x;  // 0..63
  int count = 0;
  for (int base = 0; base < S_; base += 64) {
    int k = base + lane;
    bool allowed;
    if (k == s) allowed = true;
    else if (s < N_ && k >= N_) allowed = pcm[(k - N_) * N_ + s] != 0;
    else if (s >= N_ && k < N_) allowed = pcm[(s - N_) * N_ + k] != 0;
    else allowed = false;
    unsigned long long bal = __ballot(allowed);
    if (allowed) {
      int slot = count + __popcll(bal & ((1ull << lane) - 1ull));
      if (slot < MAXDEG) adj[s * MAXDEG + slot] = k;
    }
    count += __popcll(bal);
  }
  if (lane == 0) adjcnt[s] = count < MAXDEG ? count : MAXDEG;
}

// ---------------------------------------------------------------------------
// LayerNorm (two-pass, matches jnp.mean/var) with optional FiLM te multiply
// grid = B*S blocks, 128 threads
// ---------------------------------------------------------------------------
__global__ void ln_kernel(const float* __restrict__ x, const float* __restrict__ g,
                          const float* __restrict__ b, const float* __restrict__ te,
                          float* __restrict__ out) {
  int bs = blockIdx.x;
  int tid = threadIdx.x;
  float v = x[(size_t)bs * D_ + tid];
  __shared__ float part[2];
  float sum = v;
  for (int off = 32; off; off >>= 1) sum += __shfl_xor(sum, off);
  if ((tid & 63) == 0) part[tid >> 6] = sum;
  __syncthreads();
  float mu = (part[0] + part[1]) * (1.f / 128.f);
  __syncthreads();
  float dv = v - mu;
  float sq = dv * dv;
  for (int off = 32; off; off >>= 1) sq += __shfl_xor(sq, off);
  if ((tid & 63) == 0) part[tid >> 6] = sq;
  __syncthreads();
  float var = (part[0] + part[1]) * (1.f / 128.f);
  float y = dv * rsqrtf(var + 1e-5f) * g[tid] + b[tid];
  if (te) y *= te[(bs / S_) * D_ + tid];
  out[(size_t)bs * D_ + tid] = y;
}

// ---------------------------------------------------------------------------
// Tiled fp32 GEMM: C[ROWS x Ncols] = A[ROWS x K] @ W[K x Ncols]
// MODE 0: plain; 1: C = X + A@W (X may alias C); 2: C = relu(A@W)
// 32x32 tile, 256 threads, 2x2 per thread. All dims are multiples of 32.
// ---------------------------------------------------------------------------
template <int MODE>
__global__ void gemm_kernel(const float* __restrict__ A, const float* __restrict__ W,
                            const float* __restrict__ X, float* __restrict__ C,
                            int Ncols, int K) {
  __shared__ float As[32][33];
  __shared__ float Bs[32][33];
  int tx = threadIdx.x & 15, ty = threadIdx.x >> 4;
  int row0 = blockIdx.y * 32, col0 = blockIdx.x * 32;
  float acc00 = 0.f, acc01 = 0.f, acc10 = 0.f, acc11 = 0.f;
  for (int k0 = 0; k0 < K; k0 += 32) {
    for (int i = threadIdx.x; i < 32 * 32; i += 256) {
      int r = i >> 5, c = i & 31;
      As[r][c] = A[(size_t)(row0 + r) * K + k0 + c];
      Bs[r][c] = W[(size_t)(k0 + r) * Ncols + col0 + c];
    }
    __syncthreads();
#pragma unroll
    for (int kk = 0; kk < 32; ++kk) {
      float a0 = As[ty * 2][kk], a1 = As[ty * 2 + 1][kk];
      float b0 = Bs[kk][tx * 2], b1 = Bs[kk][tx * 2 + 1];
      acc00 += a0 * b0; acc01 += a0 * b1;
      acc10 += a1 * b0; acc11 += a1 * b1;
    }
    __syncthreads();
  }
  int r = row0 + ty * 2, c = col0 + tx * 2;
  float vals[2][2] = {{acc00, acc01}, {acc10, acc11}};
#pragma unroll
  for (int i = 0; i < 2; ++i)
#pragma unroll
    for (int j = 0; j < 2; ++j) {
      float vv = vals[i][j];
      if (MODE == 1) vv += X[(size_t)(r + i) * Ncols + c + j];
      if (MODE == 2) vv = fmaxf(vv, 0.f);
      C[(size_t)(r + i) * Ncols + c + j] = vv;
    }
}

// ---------------------------------------------------------------------------
// Sparse masked attention. grid = B*S blocks, 128 threads = 8 heads x 16 dims
// ---------------------------------------------------------------------------
__global__ void attn_kernel(const float* __restrict__ q, const float* __restrict__ k,
                            const float* __restrict__ v, const int* __restrict__ adj,
                            const int* __restrict__ adjcnt, float* __restrict__ o) {
  int bs = blockIdx.x;
  int s = bs % S_;
  int bbase = bs - s;  // b*S
  int tid = threadIdx.x;
  int h = tid >> 4, d = tid & 15;
  int cnt = adjcnt[s];
  __shared__ int keys[MAXDEG];
  __shared__ float sc[8][MAXDEG];
  for (int j = tid; j < cnt; j += 128) keys[j] = adj[s * MAXDEG + j];
  __syncthreads();
  float qd = q[(size_t)bs * D_ + h * 16 + d];
  for (int j = 0; j < cnt; ++j) {
    float kd = k[(size_t)(bbase + keys[j]) * D_ + h * 16 + d];
    float p = qd * kd;
    for (int off = 8; off; off >>= 1) p += __shfl_xor(p, off, 16);
    if (d == 0) sc[h][j] = p * 0.25f;  // 1/sqrt(HD)=0.25
  }
  __syncthreads();
  float mx = -1e30f;
  for (int j = d; j < cnt; j += 16) mx = fmaxf(mx, sc[h][j]);
  for (int off = 8; off; off >>= 1) mx = fmaxf(mx, __shfl_xor(mx, off, 16));
  float sum = 0.f;
  for (int j = d; j < cnt; j += 16) {
    float e = expf(sc[h][j] - mx);
    sc[h][j] = e;
    sum += e;
  }
  for (int off = 8; off; off >>= 1) sum += __shfl_xor(sum, off, 16);
  __syncthreads();
  float acc = 0.f;
  for (int j = 0; j < cnt; ++j)
    acc += sc[h][j] * v[(size_t)(bbase + keys[j]) * D_ + h * 16 + d];
  o[(size_t)bs * D_ + tid] = acc / sum;
}

// ---------------------------------------------------------------------------
// Final head: out[b,s] = x[b,s,:] @ fc_w + fc_b. One wave per row.
// ---------------------------------------------------------------------------
__global__ void fc_kernel(const float* __restrict__ x, const float* __restrict__ w,
                          const float* __restrict__ bias, float* __restrict__ out) {
  int row = blockIdx.x;
  int lane = threadIdx.x;  // 0..63
  const float* xr = x + (size_t)row * D_;
  float vv = xr[lane] * w[lane] + xr[lane + 64] * w[lane + 64];
  for (int off = 32; off; off >>= 1) vv += __shfl_xor(vv, off);
  if (lane == 0) out[row] = vv + bias[0];
}

// ---------------------------------------------------------------------------
extern "C" void kernel_launch(void* const* d_in, const int* in_sizes, int n_in,
                              void* d_out, int out_size, void* d_ws, size_t ws_size,
                              hipStream_t stream) {
  const float* r_t       = (const float*)d_in[0];
  const int*   t         = (const int*)d_in[1];
  const int*   pcm       = (const int*)d_in[2];
  // d_in[3] = mask: unused, adjacency derived from pcm (identical support)
  const float* src_embed = (const float*)d_in[4];
  const float* time_tab  = (const float*)d_in[5];
  const float* Wq = (const float*)d_in[6];
  const float* Wk = (const float*)d_in[7];
  const float* Wv = (const float*)d_in[8];
  const float* Wo = (const float*)d_in[9];
  const float* W1 = (const float*)d_in[10];
  const float* W2 = (const float*)d_in[11];
  const float* g1 = (const float*)d_in[12];
  const float* b1 = (const float*)d_in[13];
  const float* g2 = (const float*)d_in[14];
  const float* b2 = (const float*)d_in[15];
  const float* fc_w = (const float*)d_in[16];
  const float* fc_b = (const float*)d_in[17];
  float* out = (float*)d_out;

  char* ws = (char*)d_ws;
  size_t off = 0;
  auto alloc = [&](size_t bytes) -> void* {
    void* p = ws + off;
    off = (off + bytes + 255) & ~(size_t)255;
    return p;
  };
  float* x     = (float*)alloc((size_t)ROWS * D_ * 4);
  float* h     = (float*)alloc((size_t)ROWS * D_ * 4);
  float* qb    = (float*)alloc((size_t)ROWS * D_ * 4);
  float* kb    = (float*)alloc((size_t)ROWS * D_ * 4);
  float* vb    = (float*)alloc((size_t)ROWS * D_ * 4);
  float* ob    = (float*)alloc((size_t)ROWS * D_ * 4);
  float* hf    = (float*)alloc((size_t)ROWS * DFF_ * 4);
  float* nodes = (float*)alloc((size_t)B_ * S_ * 4);
  float* te    = (float*)alloc((size_t)B_ * D_ * 4);
  int*   adj   = (int*)alloc((size_t)S_ * MAXDEG * 4);
  int*   adjc  = (int*)alloc((size_t)S_ * 4);

  nodes_kernel<<<(B_ * S_ + 255) / 256, 256, 0, stream>>>(r_t, pcm, nodes);
  te_kernel<<<(B_ * D_ + 63) / 64, 64, 0, stream>>>(t, time_tab, te);
  adj_kernel<<<S_, 64, 0, stream>>>(pcm, adj, adjc);
  xinit_kernel<<<(B_ * S_ * D_ + 255) / 256, 256, 0, stream>>>(nodes, src_embed, te, x);

  dim3 gD(D_ / 32, ROWS / 32);     // 4 x 384
  dim3 gF(DFF_ / 32, ROWS / 32);   // 16 x 384

  for (int l = 0; l < L_; ++l) {
    ln_kernel<<<ROWS, 128, 0, stream>>>(x, g1 + l * D_, b1 + l * D_, nullptr, h);
    gemm_kernel<0><<<gD, 256, 0, stream>>>(h, Wq + (size_t)l * D_ * D_, nullptr, qb, D_, D_);
    gemm_kernel<0><<<gD, 256, 0, stream>>>(h, Wk + (size_t)l * D_ * D_, nullptr, kb, D_, D_);
    gemm_kernel<0><<<gD, 256, 0, stream>>>(h, Wv + (size_t)l * D_ * D_, nullptr, vb, D_, D_);
    attn_kernel<<<ROWS, 128, 0, stream>>>(qb, kb, vb, adj, adjc, ob);
    gemm_kernel<1><<<gD, 256, 0, stream>>>(ob, Wo + (size_t)l * D_ * D_, x, x, D_, D_);
    ln_kernel<<<ROWS, 128, 0, stream>>>(x, g2 + l * D_, b2 + l * D_, te, h);
    gemm_kernel<2><<<gF, 256, 0, stream>>>(h, W1 + (size_t)l * D_ * DFF_, nullptr, hf, DFF_, D_);
    gemm_kernel<1><<<gD, 256, 0, stream>>>(hf, W2 + (size_t)l * DFF_ * D_, x, x, D_, DFF_);
  }
  fc_kernel<<<ROWS, 64, 0, stream>>>(x, fc_w, fc_b, out);
}

// Round 2
// 676.228 us; speedup vs baseline: 2.4086x; 2.4086x over previous
//
#include <hip/hip_runtime.h>
#include <cmath>
#include <cstdint>

// Problem constants (from reference)
constexpr int B_ = 8, N_ = 1024, M_ = 512, D_ = 128, S_ = 1536, L_ = 6, DFF_ = 512;
constexpr int ROWS = B_ * S_;   // 12288
constexpr int MAXDEG = 64;      // max attention row degree (actual ~7-20)

typedef __bf16 bf16x8 __attribute__((ext_vector_type(8)));
typedef float  f32x4  __attribute__((ext_vector_type(4)));

__device__ inline unsigned short f2bf(float f) {  // RNE fp32 -> bf16
  unsigned u = __float_as_uint(f);
  u += 0x7fffu + ((u >> 16) & 1u);
  return (unsigned short)(u >> 16);
}

// ---------------------------------------------------------------------------
// Adjacency from pcm: allowed(s,k) = (s==k) | Tanner edge. One wave per row.
// exp(-1e9-max) underflows to 0 in fp32 => sparse attention over this list is
// bit-equivalent to the dense masked softmax.
// ---------------------------------------------------------------------------
__global__ void adj_kernel(const int* __restrict__ pcm, int* __restrict__ adj,
                           int* __restrict__ adjcnt) {
  int s = blockIdx.x;
  int lane = threadIdx.x;  // 0..63
  int count = 0;
  for (int base = 0; base < S_; base += 64) {
    int k = base + lane;
    bool allowed;
    if (k == s) allowed = true;
    else if (s < N_ && k >= N_) allowed = pcm[(k - N_) * N_ + s] != 0;
    else if (s >= N_ && k < N_) allowed = pcm[(s - N_) * N_ + k] != 0;
    else allowed = false;
    unsigned long long bal = __ballot(allowed);
    if (allowed) {
      int slot = count + __popcll(bal & ((1ull << lane) - 1ull));
      if (slot < MAXDEG) adj[s * MAXDEG + slot] = k;
    }
    count += __popcll(bal);
  }
  if (lane == 0) adjcnt[s] = count < MAXDEG ? count : MAXDEG;
}

// ---------------------------------------------------------------------------
// nodes = [|r_t| , syndrome] using check adjacency (avg ~6 taps, not 1024)
// ---------------------------------------------------------------------------
__global__ void nodes_kernel(const float* __restrict__ r_t, const int* __restrict__ adj,
                             const int* __restrict__ adjcnt, float* __restrict__ nodes) {
  int idx = blockIdx.x * blockDim.x + threadIdx.x;
  if (idx >= B_ * S_) return;
  int b = idx / S_, s = idx % S_;
  if (s < N_) {
    nodes[idx] = fabsf(r_t[b * N_ + s]);
  } else {
    int cnt = adjcnt[s];
    float sum = 0.f;
    for (int j = 0; j < cnt; ++j) {
      int k = adj[s * MAXDEG + j];
      if (k < N_) {
        float r = r_t[b * N_ + k];
        sum += (r < 0.f) ? 1.f : (r > 0.f ? 0.f : 0.5f);  // bits = 0.5*(1-sign)
      }
    }
    nodes[idx] = fmodf(sum, 2.0f);
  }
}

// te[b,d] = time_table[t[b], d]
__global__ void te_kernel(const int* __restrict__ t, const float* __restrict__ table,
                          float* __restrict__ te) {
  int idx = blockIdx.x * blockDim.x + threadIdx.x;
  if (idx >= B_ * D_) return;
  int b = idx / D_, d = idx % D_;
  te[idx] = table[t[b] * D_ + d];
}

// x[b,s,d] = te[b,d] * src_embed[s,d] * nodes[b,s]
__global__ void xinit_kernel(const float* __restrict__ nodes, const float* __restrict__ se,
                             const float* __restrict__ te, float* __restrict__ x) {
  int idx = blockIdx.x * blockDim.x + threadIdx.x;
  if (idx >= B_ * S_ * D_) return;
  int d = idx % D_;
  int bs = idx / D_;
  int b = bs / S_, s = bs % S_;
  x[idx] = te[b * D_ + d] * se[s * D_ + d] * nodes[bs];
}

// ---------------------------------------------------------------------------
// Weight convert: fp32 [K][N] -> bf16 transposed [N][K], per layer packed as
//   [3*128][128] (q,k,v) | [128][128] (o) | [512][128] (w1) | [128][512] (w2)
// ---------------------------------------------------------------------------
constexpr int WSEG_QKV = 3 * D_ * D_;            // 49152
constexpr int WSEG_O   = D_ * D_;                // 16384
constexpr int WSEG_1   = D_ * DFF_;              // 65536
constexpr int WSEG_2   = DFF_ * D_;              // 65536
constexpr int WLAYER   = WSEG_QKV + WSEG_O + WSEG_1 + WSEG_2;  // 196608

__global__ void wconv_kernel(const float* __restrict__ Wq, const float* __restrict__ Wk,
                             const float* __restrict__ Wv, const float* __restrict__ Wo,
                             const float* __restrict__ W1, const float* __restrict__ W2,
                             unsigned short* __restrict__ out) {
  int idx = blockIdx.x * blockDim.x + threadIdx.x;
  if (idx >= L_ * WLAYER) return;
  int l = idx / WLAYER, r = idx % WLAYER;
  float v;
  if (r < WSEG_QKV) {
    int which = r / (D_ * D_), i = r % (D_ * D_);
    int n = i / D_, kk = i % D_;
    const float* W = which == 0 ? Wq : (which == 1 ? Wk : Wv);
    v = W[(size_t)l * D_ * D_ + kk * D_ + n];
  } else if (r < WSEG_QKV + WSEG_O) {
    int i = r - WSEG_QKV;
    int n = i / D_, kk = i % D_;
    v = Wo[(size_t)l * D_ * D_ + kk * D_ + n];
  } else if (r < WSEG_QKV + WSEG_O + WSEG_1) {
    int i = r - WSEG_QKV - WSEG_O;
    int n = i / D_, kk = i % D_;          // n in [0,512), kk in [0,128)
    v = W1[(size_t)l * D_ * DFF_ + kk * DFF_ + n];
  } else {
    int i = r - WSEG_QKV - WSEG_O - WSEG_1;
    int n = i / DFF_, kk = i % DFF_;      // n in [0,128), kk in [0,512)
    v = W2[(size_t)l * DFF_ * D_ + kk * D_ + n];
  }
  out[idx] = f2bf(v);
}

// ---------------------------------------------------------------------------
// LayerNorm (two-pass, matches jnp.mean/var), optional FiLM te multiply,
// bf16 output. grid = B*S blocks, 128 threads.
// ---------------------------------------------------------------------------
__global__ void ln_kernel(const float* __restrict__ x, const float* __restrict__ g,
                          const float* __restrict__ b, const float* __restrict__ te,
                          unsigned short* __restrict__ out) {
  int bs = blockIdx.x;
  int tid = threadIdx.x;
  float v = x[(size_t)bs * D_ + tid];
  __shared__ float part[2];
  float sum = v;
  for (int off = 32; off; off >>= 1) sum += __shfl_xor(sum, off);
  if ((tid & 63) == 0) part[tid >> 6] = sum;
  __syncthreads();
  float mu = (part[0] + part[1]) * (1.f / 128.f);
  __syncthreads();
  float dv = v - mu;
  float sq = dv * dv;
  for (int off = 32; off; off >>= 1) sq += __shfl_xor(sq, off);
  if ((tid & 63) == 0) part[tid >> 6] = sq;
  __syncthreads();
  float var = (part[0] + part[1]) * (1.f / 128.f);
  float y = dv * rsqrtf(var + 1e-5f) * g[tid] + b[tid];
  if (te) y *= te[(bs / S_) * D_ + tid];
  out[(size_t)bs * D_ + tid] = f2bf(y);
}

// ---------------------------------------------------------------------------
// MFMA bf16 GEMM: C[ROWS x Ncols] = A[ROWS x KTOT] @ W[KTOT x Ncols]
// A: bf16 row-major [row][KTOT]. Wt: bf16 TRANSPOSED [n][KTOT].
// Block: 256 thr (4 waves), 128 rows x 128 cols; wave = 32 rows x 128 cols
// as 2x8 tiles of 16x16, K in chunks of 128 (4 MFMA steps of K=32).
// LDS 64 KB, XOR-swizzled 16B chunks (2-way conflicts only).
// MODE 0: fp32 store; 1: fp32 C = X + acc (X may alias C); 2: bf16 relu.
// ---------------------------------------------------------------------------
template <int KTOT, int MODE>
__global__ void gemm_mfma(const unsigned short* __restrict__ A,
                          const unsigned short* __restrict__ Wt,
                          const float* __restrict__ X, float* __restrict__ Cf,
                          unsigned short* __restrict__ Cb, int ldc) {
  __shared__ unsigned short As[128 * 128];
  __shared__ unsigned short Bs[128 * 128];
  const int row0 = blockIdx.y * 128, col0 = blockIdx.x * 128;
  const int w = threadIdx.x >> 6, lane = threadIdx.x & 63;
  const int quad = lane >> 4, l16 = lane & 15;

  f32x4 acc[2][8];
#pragma unroll
  for (int i = 0; i < 2; ++i)
#pragma unroll
    for (int j = 0; j < 8; ++j) acc[i][j] = f32x4{0.f, 0.f, 0.f, 0.f};

  for (int k0 = 0; k0 < KTOT; k0 += 128) {
    // stage A[128][128] and B[128][128] bf16 chunks, swizzled
    for (int i = threadIdx.x; i < 2048; i += 256) {
      int r = i >> 4, c = i & 15;
      int sw = ((c ^ (r & 15)) << 3);
      uint4 va = *(const uint4*)&A[(size_t)(row0 + r) * KTOT + k0 + c * 8];
      *(uint4*)&As[r * 128 + sw] = va;
      uint4 vb = *(const uint4*)&Wt[(size_t)(col0 + r) * KTOT + k0 + c * 8];
      *(uint4*)&Bs[r * 128 + sw] = vb;
    }
    __syncthreads();
#pragma unroll
    for (int kk = 0; kk < 4; ++kk) {
      int cb = kk * 4 + quad;  // 16B chunk index along K
      bf16x8 a[2];
#pragma unroll
      for (int rt = 0; rt < 2; ++rt) {
        int row = w * 32 + rt * 16 + l16;
        uint4 u = *(const uint4*)&As[row * 128 + ((cb ^ (row & 15)) << 3)];
        a[rt] = __builtin_bit_cast(bf16x8, u);
      }
      bf16x8 bfr[8];
#pragma unroll
      for (int ct = 0; ct < 8; ++ct) {
        int n = ct * 16 + l16;
        uint4 u = *(const uint4*)&Bs[n * 128 + ((cb ^ (n & 15)) << 3)];
        bfr[ct] = __builtin_bit_cast(bf16x8, u);
      }
#pragma unroll
      for (int rt = 0; rt < 2; ++rt)
#pragma unroll
        for (int ct = 0; ct < 8; ++ct)
          acc[rt][ct] = __builtin_amdgcn_mfma_f32_16x16x32_bf16(a[rt], bfr[ct], acc[rt][ct], 0, 0, 0);
    }
    __syncthreads();
  }

  // epilogue: C/D layout col=lane&15, row=quad*4+reg
#pragma unroll
  for (int rt = 0; rt < 2; ++rt)
#pragma unroll
    for (int ct = 0; ct < 8; ++ct)
#pragma unroll
      for (int i = 0; i < 4; ++i) {
        int row = row0 + w * 32 + rt * 16 + quad * 4 + i;
        int col = col0 + ct * 16 + l16;
        size_t off = (size_t)row * ldc + col;
        float v = acc[rt][ct][i];
        if (MODE == 0) Cf[off] = v;
        if (MODE == 1) Cf[off] = X[off] + v;
        if (MODE == 2) Cb[off] = f2bf(fmaxf(v, 0.f));
      }
}

// ---------------------------------------------------------------------------
// Sparse masked attention. grid = B*S blocks, 128 thr = 8 heads x 16 dims.
// qkv packed [row][384] fp32 (q|k|v). Output bf16.
// ---------------------------------------------------------------------------
__global__ void attn_kernel(const float* __restrict__ qkv, const int* __restrict__ adj,
                            const int* __restrict__ adjcnt, unsigned short* __restrict__ o) {
  int bs = blockIdx.x;
  int s = bs % S_;
  int bbase = bs - s;  // b*S
  int tid = threadIdx.x;
  int h = tid >> 4, d = tid & 15;
  int cnt = adjcnt[s];
  __shared__ int keys[MAXDEG];
  __shared__ float sc[8][MAXDEG];
  for (int j = tid; j < cnt; j += 128) keys[j] = adj[s * MAXDEG + j];
  __syncthreads();
  float qd = qkv[(size_t)bs * 384 + h * 16 + d];
  for (int j = 0; j < cnt; ++j) {
    float kd = qkv[(size_t)(bbase + keys[j]) * 384 + 128 + h * 16 + d];
    float p = qd * kd;
    for (int off = 8; off; off >>= 1) p += __shfl_xor(p, off, 16);
    if (d == 0) sc[h][j] = p * 0.25f;  // 1/sqrt(HD)=0.25
  }
  __syncthreads();
  float mx = -1e30f;
  for (int j = d; j < cnt; j += 16) mx = fmaxf(mx, sc[h][j]);
  for (int off = 8; off; off >>= 1) mx = fmaxf(mx, __shfl_xor(mx, off, 16));
  float sum = 0.f;
  for (int j = d; j < cnt; j += 16) {
    float e = expf(sc[h][j] - mx);
    sc[h][j] = e;
    sum += e;
  }
  for (int off = 8; off; off >>= 1) sum += __shfl_xor(sum, off, 16);
  __syncthreads();
  float acc = 0.f;
  for (int j = 0; j < cnt; ++j)
    acc += sc[h][j] * qkv[(size_t)(bbase + keys[j]) * 384 + 256 + h * 16 + d];
  o[(size_t)bs * D_ + tid] = f2bf(acc / sum);
}

// ---------------------------------------------------------------------------
// Final head: out[b,s] = x[b,s,:] @ fc_w + fc_b. One wave per row.
// ---------------------------------------------------------------------------
__global__ void fc_kernel(const float* __restrict__ x, const float* __restrict__ w,
                          const float* __restrict__ bias, float* __restrict__ out) {
  int row = blockIdx.x;
  int lane = threadIdx.x;  // 0..63
  const float* xr = x + (size_t)row * D_;
  float vv = xr[lane] * w[lane] + xr[lane + 64] * w[lane + 64];
  for (int off = 32; off; off >>= 1) vv += __shfl_xor(vv, off);
  if (lane == 0) out[row] = vv + bias[0];
}

// ---------------------------------------------------------------------------
extern "C" void kernel_launch(void* const* d_in, const int* in_sizes, int n_in,
                              void* d_out, int out_size, void* d_ws, size_t ws_size,
                              hipStream_t stream) {
  const float* r_t       = (const float*)d_in[0];
  const int*   t         = (const int*)d_in[1];
  const int*   pcm       = (const int*)d_in[2];
  // d_in[3] = mask: unused, adjacency derived from pcm (identical support)
  const float* src_embed = (const float*)d_in[4];
  const float* time_tab  = (const float*)d_in[5];
  const float* Wq = (const float*)d_in[6];
  const float* Wk = (const float*)d_in[7];
  const float* Wv = (const float*)d_in[8];
  const float* Wo = (const float*)d_in[9];
  const float* W1 = (const float*)d_in[10];
  const float* W2 = (const float*)d_in[11];
  const float* g1 = (const float*)d_in[12];
  const float* b1 = (const float*)d_in[13];
  const float* g2 = (const float*)d_in[14];
  const float* b2 = (const float*)d_in[15];
  const float* fc_w = (const float*)d_in[16];
  const float* fc_b = (const float*)d_in[17];
  float* out = (float*)d_out;

  char* ws = (char*)d_ws;
  size_t off = 0;
  auto alloc = [&](size_t bytes) -> void* {
    void* p = ws + off;
    off = (off + bytes + 255) & ~(size_t)255;
    return p;
  };
  float*          x     = (float*)alloc((size_t)ROWS * D_ * 4);
  unsigned short* h     = (unsigned short*)alloc((size_t)ROWS * D_ * 2);
  float*          qkv   = (float*)alloc((size_t)ROWS * 384 * 4);
  unsigned short* ob    = (unsigned short*)alloc((size_t)ROWS * D_ * 2);
  unsigned short* hf    = (unsigned short*)alloc((size_t)ROWS * DFF_ * 2);
  float*          nodes = (float*)alloc((size_t)B_ * S_ * 4);
  float*          te    = (float*)alloc((size_t)B_ * D_ * 4);
  int*            adj   = (int*)alloc((size_t)S_ * MAXDEG * 4);
  int*            adjc  = (int*)alloc((size_t)S_ * 4);
  unsigned short* wbf   = (unsigned short*)alloc((size_t)L_ * WLAYER * 2);

  te_kernel<<<(B_ * D_ + 63) / 64, 64, 0, stream>>>(t, time_tab, te);
  adj_kernel<<<S_, 64, 0, stream>>>(pcm, adj, adjc);
  nodes_kernel<<<(B_ * S_ + 255) / 256, 256, 0, stream>>>(r_t, adj, adjc, nodes);
  xinit_kernel<<<(B_ * S_ * D_ + 255) / 256, 256, 0, stream>>>(nodes, src_embed, te, x);
  wconv_kernel<<<(L_ * WLAYER + 255) / 256, 256, 0, stream>>>(Wq, Wk, Wv, Wo, W1, W2, wbf);

  for (int l = 0; l < L_; ++l) {
    const unsigned short* wl = wbf + (size_t)l * WLAYER;
    ln_kernel<<<ROWS, 128, 0, stream>>>(x, g1 + l * D_, b1 + l * D_, nullptr, h);
    gemm_mfma<128, 0><<<dim3(3, ROWS / 128), 256, 0, stream>>>(h, wl, nullptr, qkv, nullptr, 384);
    attn_kernel<<<ROWS, 128, 0, stream>>>(qkv, adj, adjc, ob);
    gemm_mfma<128, 1><<<dim3(1, ROWS / 128), 256, 0, stream>>>(ob, wl + WSEG_QKV, x, x, nullptr, D_);
    ln_kernel<<<ROWS, 128, 0, stream>>>(x, g2 + l * D_, b2 + l * D_, te, h);
    gemm_mfma<128, 2><<<dim3(4, ROWS / 128), 256, 0, stream>>>(h, wl + WSEG_QKV + WSEG_O, nullptr, nullptr, hf, DFF_);
    gemm_mfma<512, 1><<<dim3(1, ROWS / 128), 256, 0, stream>>>(hf, wl + WSEG_QKV + WSEG_O + WSEG_1, x, x, nullptr, D_);
  }
  fc_kernel<<<ROWS, 64, 0, stream>>>(x, fc_w, fc_b, out);
}

// Round 3
// 578.086 us; speedup vs baseline: 2.8175x; 1.1698x over previous
//
#include <hip/hip_runtime.h>
#include <cmath>
#include <cstdint>

// Problem constants (from reference)
constexpr int B_ = 8, N_ = 1024, M_ = 512, D_ = 128, S_ = 1536, L_ = 6, DFF_ = 512;
constexpr int ROWS = B_ * S_;   // 12288
constexpr int MAXDEG = 64;      // max attention row degree (actual ~7-25)

typedef __bf16 bf16x8 __attribute__((ext_vector_type(8)));
typedef float  f32x4  __attribute__((ext_vector_type(4)));
typedef unsigned short u16x8 __attribute__((ext_vector_type(8)));

__device__ inline unsigned short f2bf(float f) {  // RNE fp32 -> bf16
  unsigned u = __float_as_uint(f);
  u += 0x7fffu + ((u >> 16) & 1u);
  return (unsigned short)(u >> 16);
}

// ---------------------------------------------------------------------------
// Adjacency from pcm: allowed(s,k) = (s==k) | Tanner edge. One wave per row.
// exp(-1e9-max) underflows to 0 in fp32 => sparse attention over this list is
// bit-equivalent to the dense masked softmax.
// ---------------------------------------------------------------------------
__global__ void adj_kernel(const int* __restrict__ pcm, int* __restrict__ adj,
                           int* __restrict__ adjcnt) {
  int s = blockIdx.x;
  int lane = threadIdx.x;  // 0..63
  int count = 0;
  for (int base = 0; base < S_; base += 64) {
    int k = base + lane;
    bool allowed;
    if (k == s) allowed = true;
    else if (s < N_ && k >= N_) allowed = pcm[(k - N_) * N_ + s] != 0;
    else if (s >= N_ && k < N_) allowed = pcm[(s - N_) * N_ + k] != 0;
    else allowed = false;
    unsigned long long bal = __ballot(allowed);
    if (allowed) {
      int slot = count + __popcll(bal & ((1ull << lane) - 1ull));
      if (slot < MAXDEG) adj[s * MAXDEG + slot] = k;
    }
    count += __popcll(bal);
  }
  if (lane == 0) adjcnt[s] = count < MAXDEG ? count : MAXDEG;
}

// ---------------------------------------------------------------------------
// x[b,s,d] = table[t[b],d] * src_embed[s,d] * nodes[b,s]; nodes from adjacency.
// grid = B*S blocks, 128 threads.
// ---------------------------------------------------------------------------
__global__ void xinit_kernel(const float* __restrict__ r_t, const int* __restrict__ adj,
                             const int* __restrict__ adjcnt, const float* __restrict__ se,
                             const int* __restrict__ tt, const float* __restrict__ table,
                             float* __restrict__ x) {
  int bs = blockIdx.x;
  int b = bs / S_, s = bs % S_;
  int d = threadIdx.x;
  float node;
  if (s < N_) {
    node = fabsf(r_t[b * N_ + s]);
  } else {
    int cnt = adjcnt[s];
    float sum = 0.f;
    for (int j = 0; j < cnt; ++j) {
      int k = adj[s * MAXDEG + j];
      if (k < N_) {
        float r = r_t[b * N_ + k];
        sum += (r < 0.f) ? 1.f : (r > 0.f ? 0.f : 0.5f);  // bits = 0.5*(1-sign)
      }
    }
    node = fmodf(sum, 2.0f);
  }
  x[(size_t)bs * D_ + d] = table[tt[b] * D_ + d] * se[s * D_ + d] * node;
}

// ---------------------------------------------------------------------------
// Weight convert: fp32 [K][N] -> bf16 transposed [N][K], per layer packed as
//   [3*128][128] (q,k,v) | [128][128] (o) | [512][128] (w1) | [128][512] (w2)
// ---------------------------------------------------------------------------
constexpr int WSEG_QKV = 3 * D_ * D_;            // 49152
constexpr int WSEG_O   = D_ * D_;                // 16384
constexpr int WSEG_1   = D_ * DFF_;              // 65536
constexpr int WSEG_2   = DFF_ * D_;              // 65536
constexpr int WLAYER   = WSEG_QKV + WSEG_O + WSEG_1 + WSEG_2;  // 196608

__global__ void wconv_kernel(const float* __restrict__ Wq, const float* __restrict__ Wk,
                             const float* __restrict__ Wv, const float* __restrict__ Wo,
                             const float* __restrict__ W1, const float* __restrict__ W2,
                             unsigned short* __restrict__ out) {
  int idx = blockIdx.x * blockDim.x + threadIdx.x;
  if (idx >= L_ * WLAYER) return;
  int l = idx / WLAYER, r = idx % WLAYER;
  float v;
  if (r < WSEG_QKV) {
    int which = r / (D_ * D_), i = r % (D_ * D_);
    int n = i / D_, kk = i % D_;
    const float* W = which == 0 ? Wq : (which == 1 ? Wk : Wv);
    v = W[(size_t)l * D_ * D_ + kk * D_ + n];
  } else if (r < WSEG_QKV + WSEG_O) {
    int i = r - WSEG_QKV;
    int n = i / D_, kk = i % D_;
    v = Wo[(size_t)l * D_ * D_ + kk * D_ + n];
  } else if (r < WSEG_QKV + WSEG_O + WSEG_1) {
    int i = r - WSEG_QKV - WSEG_O;
    int n = i / D_, kk = i % D_;          // n in [0,512), kk in [0,128)
    v = W1[(size_t)l * D_ * DFF_ + kk * DFF_ + n];
  } else {
    int i = r - WSEG_QKV - WSEG_O - WSEG_1;
    int n = i / DFF_, kk = i % DFF_;      // n in [0,128), kk in [0,512)
    v = W2[(size_t)l * DFF_ * D_ + kk * D_ + n];
  }
  out[idx] = f2bf(v);
}

// ---------------------------------------------------------------------------
// Shared MFMA helper: 128x128 tile (wave = 32 rows x 128 cols, 2x8 tiles of
// 16x16), K=128 in 4 steps of 32. LDS layout: 16B chunks, XOR-swizzled
// [row*128 + ((chunk ^ (row&15))<<3)].
// ---------------------------------------------------------------------------
__device__ __forceinline__ void mfma_tile(const unsigned short* As, const unsigned short* Bs,
                                          int w, int quad, int l16, f32x4 acc[2][8]) {
#pragma unroll
  for (int kk = 0; kk < 4; ++kk) {
    int cb = kk * 4 + quad;
    bf16x8 a[2];
#pragma unroll
    for (int rt = 0; rt < 2; ++rt) {
      int row = w * 32 + rt * 16 + l16;
      a[rt] = __builtin_bit_cast(bf16x8, *(const uint4*)&As[row * 128 + ((cb ^ (row & 15)) << 3)]);
    }
    bf16x8 bb[8];
#pragma unroll
    for (int ct = 0; ct < 8; ++ct) {
      int n = ct * 16 + l16;
      bb[ct] = __builtin_bit_cast(bf16x8, *(const uint4*)&Bs[n * 128 + ((cb ^ (n & 15)) << 3)]);
    }
#pragma unroll
    for (int rt = 0; rt < 2; ++rt)
#pragma unroll
      for (int ct = 0; ct < 8; ++ct)
        acc[rt][ct] = __builtin_amdgcn_mfma_f32_16x16x32_bf16(a[rt], bb[ct], acc[rt][ct], 0, 0, 0);
  }
}

// ---------------------------------------------------------------------------
// K1: LN1 (fp32, two-pass) -> bf16 tile in LDS -> QKV GEMM (N=384 loop).
// grid = 96 blocks x 256 thr. wt = [384][128] bf16 transposed weights.
// ---------------------------------------------------------------------------
__global__ void __launch_bounds__(256) k1_ln_qkv(const float* __restrict__ x,
                                                 const float* __restrict__ g1,
                                                 const float* __restrict__ b1,
                                                 const unsigned short* __restrict__ wt,
                                                 float* __restrict__ qkv) {
  __shared__ unsigned short As[128 * 128];
  __shared__ unsigned short Bs[128 * 128];
  const int row0 = blockIdx.x * 128;
  const int t = threadIdx.x, w = t >> 6, lane = t & 63, quad = lane >> 4, l16 = lane & 15;
  {  // LN: 2 threads per row; wave w covers rows [32w,32w+32) = its MFMA rows
    const int r = t >> 1, half = t & 1;
    const float* xr = x + (size_t)(row0 + r) * D_ + half * 64;
    f32x4 xv[16];
#pragma unroll
    for (int i = 0; i < 16; ++i) xv[i] = *(const f32x4*)(xr + 4 * i);
    float s = 0.f;
#pragma unroll
    for (int i = 0; i < 16; ++i) s += xv[i][0] + xv[i][1] + xv[i][2] + xv[i][3];
    s += __shfl_xor(s, 1);
    const float mu = s * (1.f / 128.f);
    float sq = 0.f;
#pragma unroll
    for (int i = 0; i < 16; ++i)
#pragma unroll
      for (int j = 0; j < 4; ++j) { float d = xv[i][j] - mu; sq += d * d; }
    sq += __shfl_xor(sq, 1);
    const float rstd = rsqrtf(sq * (1.f / 128.f) + 1e-5f);
    const int c0 = half * 64;
#pragma unroll
    for (int k = 0; k < 8; ++k) {
      u16x8 pk;
#pragma unroll
      for (int j = 0; j < 8; ++j) {
        int idx = k * 8 + j;
        pk[j] = f2bf((xv[idx >> 2][idx & 3] - mu) * rstd * g1[c0 + idx] + b1[c0 + idx]);
      }
      int c = (c0 >> 3) + k;
      *(u16x8*)&As[r * 128 + ((c ^ (r & 15)) << 3)] = pk;
    }
  }
  for (int nt = 0; nt < 3; ++nt) {
    for (int i = t; i < 2048; i += 256) {
      int rr = i >> 4, cc = i & 15;
      uint4 vb = *(const uint4*)&wt[(size_t)(nt * 128 + rr) * 128 + cc * 8];
      *(uint4*)&Bs[rr * 128 + ((cc ^ (rr & 15)) << 3)] = vb;
    }
    __syncthreads();
    f32x4 acc[2][8];
#pragma unroll
    for (int i = 0; i < 2; ++i)
#pragma unroll
      for (int j = 0; j < 8; ++j) acc[i][j] = f32x4{0.f, 0.f, 0.f, 0.f};
    mfma_tile(As, Bs, w, quad, l16, acc);
#pragma unroll
    for (int rt = 0; rt < 2; ++rt)
#pragma unroll
      for (int ct = 0; ct < 8; ++ct)
#pragma unroll
        for (int i = 0; i < 4; ++i) {
          int row = row0 + w * 32 + rt * 16 + quad * 4 + i;
          int col = nt * 128 + ct * 16 + l16;
          qkv[(size_t)row * 384 + col] = acc[rt][ct][i];
        }
    __syncthreads();  // before next Bs overwrite
  }
}

// ---------------------------------------------------------------------------
// K2: sparse masked attention. grid = B*S blocks, 128 thr = 8 heads x 16 dims.
// qkv packed [row][384] fp32 (q|k|v). Output bf16.
// ---------------------------------------------------------------------------
__global__ void attn_kernel(const float* __restrict__ qkv, const int* __restrict__ adj,
                            const int* __restrict__ adjcnt, unsigned short* __restrict__ o) {
  int bs = blockIdx.x;
  int s = bs % S_;
  int bbase = bs - s;  // b*S
  int tid = threadIdx.x;
  int h = tid >> 4, d = tid & 15;
  int cnt = adjcnt[s];
  __shared__ int keys[MAXDEG];
  __shared__ float sc[8][MAXDEG];
  for (int j = tid; j < cnt; j += 128) keys[j] = adj[s * MAXDEG + j];
  __syncthreads();
  float qd = qkv[(size_t)bs * 384 + h * 16 + d];
  for (int j = 0; j < cnt; ++j) {
    float kd = qkv[(size_t)(bbase + keys[j]) * 384 + 128 + h * 16 + d];
    float p = qd * kd;
    for (int off = 8; off; off >>= 1) p += __shfl_xor(p, off, 16);
    if (d == 0) sc[h][j] = p * 0.25f;  // 1/sqrt(HD)=0.25
  }
  __syncthreads();
  float mx = -1e30f;
  for (int j = d; j < cnt; j += 16) mx = fmaxf(mx, sc[h][j]);
  for (int off = 8; off; off >>= 1) mx = fmaxf(mx, __shfl_xor(mx, off, 16));
  float sum = 0.f;
  for (int j = d; j < cnt; j += 16) {
    float e = expf(sc[h][j] - mx);
    sc[h][j] = e;
    sum += e;
  }
  for (int off = 8; off; off >>= 1) sum += __shfl_xor(sum, off, 16);
  __syncthreads();
  float acc = 0.f;
  for (int j = 0; j < cnt; ++j)
    acc += sc[h][j] * qkv[(size_t)(bbase + keys[j]) * 384 + 256 + h * 16 + d];
  o[(size_t)bs * D_ + tid] = f2bf(acc / sum);
}

// ---------------------------------------------------------------------------
// K3: o@Wo + x -> LN2*te -> relu(.@W1) -> @W2 -> + residual. Last layer also
// fuses the fc head. grid = 96 blocks x 256 thr, 128 rows/block.
// x' and acc2 stay in registers (MFMA C-layout); h2/hf round-trip LDS only.
// ---------------------------------------------------------------------------
template <bool LAST>
__global__ void __launch_bounds__(256) k3_rest(
    const unsigned short* __restrict__ ob, const unsigned short* __restrict__ wo,
    const unsigned short* __restrict__ w1, const unsigned short* __restrict__ w2,
    const float* __restrict__ g2, const float* __restrict__ b2,
    const int* __restrict__ tt, const float* __restrict__ table,
    float* __restrict__ x, const float* __restrict__ fcw,
    const float* __restrict__ fcb, float* __restrict__ out) {
  __shared__ unsigned short As[128 * 128];
  __shared__ unsigned short Bs[128 * 128];
  __shared__ unsigned short Cs[128 * 128];
  __shared__ float teS[128], gS[128], bS[128], fS[128];
  const int row0 = blockIdx.x * 128;
  const int t = threadIdx.x, w = t >> 6, lane = t & 63, quad = lane >> 4, l16 = lane & 15;
  if (t < 128) {
    int b = row0 / S_;  // 1536 % 128 == 0: block rows share one batch index
    teS[t] = table[tt[b] * D_ + t];
    gS[t] = g2[t];
    bS[t] = b2[t];
    if (LAST) fS[t] = fcw[t];
  }
  // stage As <- o tile (wave-private rows), Bs <- Wo^T (cooperative)
  for (int i = w * 512 + lane; i < w * 512 + 512; i += 64) {
    int rr = i >> 4, cc = i & 15;
    uint4 va = *(const uint4*)&ob[(size_t)(row0 + rr) * D_ + cc * 8];
    *(uint4*)&As[rr * 128 + ((cc ^ (rr & 15)) << 3)] = va;
  }
  for (int i = t; i < 2048; i += 256) {
    int rr = i >> 4, cc = i & 15;
    uint4 vb = *(const uint4*)&wo[(size_t)rr * 128 + cc * 8];
    *(uint4*)&Bs[rr * 128 + ((cc ^ (rr & 15)) << 3)] = vb;
  }
  __syncthreads();
  f32x4 acc1[2][8];
#pragma unroll
  for (int i = 0; i < 2; ++i)
#pragma unroll
    for (int j = 0; j < 8; ++j) acc1[i][j] = f32x4{0.f, 0.f, 0.f, 0.f};
  mfma_tile(As, Bs, w, quad, l16, acc1);
  // x' = x + o@Wo, held in C-layout registers
  f32x4 xp[2][8];
#pragma unroll
  for (int rt = 0; rt < 2; ++rt)
#pragma unroll
    for (int ct = 0; ct < 8; ++ct)
#pragma unroll
      for (int i = 0; i < 4; ++i) {
        int row = row0 + w * 32 + rt * 16 + quad * 4 + i;
        int col = ct * 16 + l16;
        xp[rt][ct][i] = x[(size_t)row * D_ + col] + acc1[rt][ct][i];
      }
  // LN2 per row: row (w,rt,quad,i) is spread over 16 lanes (l16) x 8 regs (ct)
  float mu_[2][4], rs_[2][4];
#pragma unroll
  for (int rt = 0; rt < 2; ++rt)
#pragma unroll
    for (int i = 0; i < 4; ++i) {
      float s = 0.f;
#pragma unroll
      for (int ct = 0; ct < 8; ++ct) s += xp[rt][ct][i];
      for (int off = 1; off < 16; off <<= 1) s += __shfl_xor(s, off);
      float mu = s * (1.f / 128.f);
      float sq = 0.f;
#pragma unroll
      for (int ct = 0; ct < 8; ++ct) { float d = xp[rt][ct][i] - mu; sq += d * d; }
      for (int off = 1; off < 16; off <<= 1) sq += __shfl_xor(sq, off);
      mu_[rt][i] = mu;
      rs_[rt][i] = rsqrtf(sq * (1.f / 128.f) + 1e-5f);
    }
  __syncthreads();  // everyone done reading As(o)/Bs(Wo)
  // h2 = LN2(x')*g+b, FiLM te -> bf16 -> As (wave-private rows, A-layout)
#pragma unroll
  for (int rt = 0; rt < 2; ++rt)
#pragma unroll
    for (int ct = 0; ct < 8; ++ct)
#pragma unroll
      for (int i = 0; i < 4; ++i) {
        int rowL = w * 32 + rt * 16 + quad * 4 + i;
        int col = ct * 16 + l16;
        float h2 = (xp[rt][ct][i] - mu_[rt][i]) * rs_[rt][i] * gS[col] + bS[col];
        h2 *= teS[col];
        As[rowL * 128 + (((col >> 3) ^ (rowL & 15)) << 3) + (col & 7)] = f2bf(h2);
      }
  // FFN: hf chunk c = relu(h2 @ W1[:,c*128:+128]) -> Cs; acc2 += Cs @ W2[c-chunk]
  f32x4 acc2[2][8];
#pragma unroll
  for (int i = 0; i < 2; ++i)
#pragma unroll
    for (int j = 0; j < 8; ++j) acc2[i][j] = f32x4{0.f, 0.f, 0.f, 0.f};
  for (int c = 0; c < 4; ++c) {
    for (int i = t; i < 2048; i += 256) {  // Bs <- W1t rows [c*128, c*128+128)
      int rr = i >> 4, cc = i & 15;
      uint4 vb = *(const uint4*)&w1[(size_t)(c * 128 + rr) * 128 + cc * 8];
      *(uint4*)&Bs[rr * 128 + ((cc ^ (rr & 15)) << 3)] = vb;
    }
    __syncthreads();
    f32x4 accF[2][8];
#pragma unroll
    for (int i = 0; i < 2; ++i)
#pragma unroll
      for (int j = 0; j < 8; ++j) accF[i][j] = f32x4{0.f, 0.f, 0.f, 0.f};
    mfma_tile(As, Bs, w, quad, l16, accF);
    __syncthreads();  // all waves done reading Bs(W1)
#pragma unroll
    for (int rt = 0; rt < 2; ++rt)
#pragma unroll
      for (int ct = 0; ct < 8; ++ct)
#pragma unroll
        for (int i = 0; i < 4; ++i) {
          int rowL = w * 32 + rt * 16 + quad * 4 + i;
          int col = ct * 16 + l16;
          Cs[rowL * 128 + (((col >> 3) ^ (rowL & 15)) << 3) + (col & 7)] =
              f2bf(fmaxf(accF[rt][ct][i], 0.f));
        }
    for (int i = t; i < 2048; i += 256) {  // Bs <- W2t k-chunk c
      int rr = i >> 4, cc = i & 15;
      uint4 vb = *(const uint4*)&w2[(size_t)rr * 512 + c * 128 + cc * 8];
      *(uint4*)&Bs[rr * 128 + ((cc ^ (rr & 15)) << 3)] = vb;
    }
    __syncthreads();
    mfma_tile(Cs, Bs, w, quad, l16, acc2);
    __syncthreads();  // before next c overwrites Bs
  }
  // epilogue: x'' = x' + ffn
  if (!LAST) {
#pragma unroll
    for (int rt = 0; rt < 2; ++rt)
#pragma unroll
      for (int ct = 0; ct < 8; ++ct)
#pragma unroll
        for (int i = 0; i < 4; ++i) {
          int row = row0 + w * 32 + rt * 16 + quad * 4 + i;
          int col = ct * 16 + l16;
          x[(size_t)row * D_ + col] = xp[rt][ct][i] + acc2[rt][ct][i];
        }
  } else {
    float pr[2][4] = {{0.f, 0.f, 0.f, 0.f}, {0.f, 0.f, 0.f, 0.f}};
#pragma unroll
    for (int rt = 0; rt < 2; ++rt)
#pragma unroll
      for (int ct = 0; ct < 8; ++ct)
#pragma unroll
        for (int i = 0; i < 4; ++i) {
          int col = ct * 16 + l16;
          pr[rt][i] += (xp[rt][ct][i] + acc2[rt][ct][i]) * fS[col];
        }
#pragma unroll
    for (int rt = 0; rt < 2; ++rt)
#pragma unroll
      for (int i = 0; i < 4; ++i) {
        float s = pr[rt][i];
        for (int off = 1; off < 16; off <<= 1) s += __shfl_xor(s, off);
        if (l16 == 0) {
          int row = row0 + w * 32 + rt * 16 + quad * 4 + i;
          out[row] = s + fcb[0];
        }
      }
  }
}

// ---------------------------------------------------------------------------
extern "C" void kernel_launch(void* const* d_in, const int* in_sizes, int n_in,
                              void* d_out, int out_size, void* d_ws, size_t ws_size,
                              hipStream_t stream) {
  const float* r_t       = (const float*)d_in[0];
  const int*   t         = (const int*)d_in[1];
  const int*   pcm       = (const int*)d_in[2];
  // d_in[3] = mask: unused, adjacency derived from pcm (identical support)
  const float* src_embed = (const float*)d_in[4];
  const float* time_tab  = (const float*)d_in[5];
  const float* Wq = (const float*)d_in[6];
  const float* Wk = (const float*)d_in[7];
  const float* Wv = (const float*)d_in[8];
  const float* Wo = (const float*)d_in[9];
  const float* W1 = (const float*)d_in[10];
  const float* W2 = (const float*)d_in[11];
  const float* g1 = (const float*)d_in[12];
  const float* b1 = (const float*)d_in[13];
  const float* g2 = (const float*)d_in[14];
  const float* b2 = (const float*)d_in[15];
  const float* fc_w = (const float*)d_in[16];
  const float* fc_b = (const float*)d_in[17];
  float* out = (float*)d_out;

  char* ws = (char*)d_ws;
  size_t off = 0;
  auto alloc = [&](size_t bytes) -> void* {
    void* p = ws + off;
    off = (off + bytes + 255) & ~(size_t)255;
    return p;
  };
  float*          x    = (float*)alloc((size_t)ROWS * D_ * 4);
  float*          qkv  = (float*)alloc((size_t)ROWS * 384 * 4);
  unsigned short* ob   = (unsigned short*)alloc((size_t)ROWS * D_ * 2);
  int*            adj  = (int*)alloc((size_t)S_ * MAXDEG * 4);
  int*            adjc = (int*)alloc((size_t)S_ * 4);
  unsigned short* wbf  = (unsigned short*)alloc((size_t)L_ * WLAYER * 2);

  adj_kernel<<<S_, 64, 0, stream>>>(pcm, adj, adjc);
  wconv_kernel<<<(L_ * WLAYER + 255) / 256, 256, 0, stream>>>(Wq, Wk, Wv, Wo, W1, W2, wbf);
  xinit_kernel<<<ROWS, 128, 0, stream>>>(r_t, adj, adjc, src_embed, t, time_tab, x);

  for (int l = 0; l < L_; ++l) {
    const unsigned short* wl = wbf + (size_t)l * WLAYER;
    k1_ln_qkv<<<ROWS / 128, 256, 0, stream>>>(x, g1 + l * D_, b1 + l * D_, wl, qkv);
    attn_kernel<<<ROWS, 128, 0, stream>>>(qkv, adj, adjc, ob);
    if (l < L_ - 1) {
      k3_rest<false><<<ROWS / 128, 256, 0, stream>>>(
          ob, wl + WSEG_QKV, wl + WSEG_QKV + WSEG_O, wl + WSEG_QKV + WSEG_O + WSEG_1,
          g2 + l * D_, b2 + l * D_, t, time_tab, x, nullptr, nullptr, nullptr);
    } else {
      k3_rest<true><<<ROWS / 128, 256, 0, stream>>>(
          ob, wl + WSEG_QKV, wl + WSEG_QKV + WSEG_O, wl + WSEG_QKV + WSEG_O + WSEG_1,
          g2 + l * D_, b2 + l * D_, t, time_tab, x, fc_w, fc_b, out);
    }
  }
}

// Round 4
// 508.508 us; speedup vs baseline: 3.2030x; 1.1368x over previous
//
#include <hip/hip_runtime.h>
#include <cmath>
#include <cstdint>

// Problem constants (from reference)
constexpr int B_ = 8, N_ = 1024, M_ = 512, D_ = 128, S_ = 1536, L_ = 6, DFF_ = 512;
constexpr int ROWS = B_ * S_;   // 12288
constexpr int MAXDEG = 64;      // max attention row degree (actual ~7-25)

typedef __bf16 bf16x8 __attribute__((ext_vector_type(8)));
typedef float  f32x4  __attribute__((ext_vector_type(4)));
typedef unsigned short u16x8 __attribute__((ext_vector_type(8)));

__device__ inline unsigned short f2bf(float f) {  // RNE fp32 -> bf16
  unsigned u = __float_as_uint(f);
  u += 0x7fffu + ((u >> 16) & 1u);
  return (unsigned short)(u >> 16);
}

// ---------------------------------------------------------------------------
// Adjacency from pcm: allowed(s,k) = (s==k) | Tanner edge. One wave per row.
// exp(-1e9-max) underflows to 0 in fp32 => sparse attention over this list is
// bit-equivalent to the dense masked softmax.
// ---------------------------------------------------------------------------
__global__ void adj_kernel(const int* __restrict__ pcm, int* __restrict__ adj,
                           int* __restrict__ adjcnt) {
  int s = blockIdx.x;
  int lane = threadIdx.x;  // 0..63
  int count = 0;
  for (int base = 0; base < S_; base += 64) {
    int k = base + lane;
    bool allowed;
    if (k == s) allowed = true;
    else if (s < N_ && k >= N_) allowed = pcm[(k - N_) * N_ + s] != 0;
    else if (s >= N_ && k < N_) allowed = pcm[(s - N_) * N_ + k] != 0;
    else allowed = false;
    unsigned long long bal = __ballot(allowed);
    if (allowed) {
      int slot = count + __popcll(bal & ((1ull << lane) - 1ull));
      if (slot < MAXDEG) adj[s * MAXDEG + slot] = k;
    }
    count += __popcll(bal);
  }
  if (lane == 0) adjcnt[s] = count < MAXDEG ? count : MAXDEG;
}

// ---------------------------------------------------------------------------
// x[b,s,d] = table[t[b],d] * src_embed[s,d] * nodes[b,s]; nodes from adjacency.
// ---------------------------------------------------------------------------
__global__ void xinit_kernel(const float* __restrict__ r_t, const int* __restrict__ adj,
                             const int* __restrict__ adjcnt, const float* __restrict__ se,
                             const int* __restrict__ tt, const float* __restrict__ table,
                             float* __restrict__ x) {
  int bs = blockIdx.x;
  int b = bs / S_, s = bs % S_;
  int d = threadIdx.x;
  float node;
  if (s < N_) {
    node = fabsf(r_t[b * N_ + s]);
  } else {
    int cnt = adjcnt[s];
    float sum = 0.f;
    for (int j = 0; j < cnt; ++j) {
      int k = adj[s * MAXDEG + j];
      if (k < N_) {
        float r = r_t[b * N_ + k];
        sum += (r < 0.f) ? 1.f : (r > 0.f ? 0.f : 0.5f);  // bits = 0.5*(1-sign)
      }
    }
    node = fmodf(sum, 2.0f);
  }
  x[(size_t)bs * D_ + d] = table[tt[b] * D_ + d] * se[s * D_ + d] * node;
}

// ---------------------------------------------------------------------------
// Weight convert: fp32 [K][N] -> bf16 transposed [N][K], per layer packed as
//   [3*128][128] (q,k,v) | [128][128] (o) | [512][128] (w1) | [128][512] (w2)
// ---------------------------------------------------------------------------
constexpr int WSEG_QKV = 3 * D_ * D_;            // 49152
constexpr int WSEG_O   = D_ * D_;                // 16384
constexpr int WSEG_1   = D_ * DFF_;              // 65536
constexpr int WSEG_2   = DFF_ * D_;              // 65536
constexpr int WLAYER   = WSEG_QKV + WSEG_O + WSEG_1 + WSEG_2;  // 196608

__global__ void wconv_kernel(const float* __restrict__ Wq, const float* __restrict__ Wk,
                             const float* __restrict__ Wv, const float* __restrict__ Wo,
                             const float* __restrict__ W1, const float* __restrict__ W2,
                             unsigned short* __restrict__ out) {
  int idx = blockIdx.x * blockDim.x + threadIdx.x;
  if (idx >= L_ * WLAYER) return;
  int l = idx / WLAYER, r = idx % WLAYER;
  float v;
  if (r < WSEG_QKV) {
    int which = r / (D_ * D_), i = r % (D_ * D_);
    int n = i / D_, kk = i % D_;
    const float* W = which == 0 ? Wq : (which == 1 ? Wk : Wv);
    v = W[(size_t)l * D_ * D_ + kk * D_ + n];
  } else if (r < WSEG_QKV + WSEG_O) {
    int i = r - WSEG_QKV;
    int n = i / D_, kk = i % D_;
    v = Wo[(size_t)l * D_ * D_ + kk * D_ + n];
  } else if (r < WSEG_QKV + WSEG_O + WSEG_1) {
    int i = r - WSEG_QKV - WSEG_O;
    int n = i / D_, kk = i % D_;          // n in [0,512), kk in [0,128)
    v = W1[(size_t)l * D_ * DFF_ + kk * DFF_ + n];
  } else {
    int i = r - WSEG_QKV - WSEG_O - WSEG_1;
    int n = i / DFF_, kk = i % DFF_;      // n in [0,128), kk in [0,512)
    v = W2[(size_t)l * DFF_ * D_ + kk * D_ + n];
  }
  out[idx] = f2bf(v);
}

// ---------------------------------------------------------------------------
// MFMA helper: wave computes 16 rows x 128 cols (1x8 tiles of 16x16), K=128
// in 4 steps of 32. LDS: 16B chunks XOR-swizzled [row*128 + ((c^(row&15))<<3)].
// ---------------------------------------------------------------------------
__device__ __forceinline__ void mfma16(const unsigned short* As, const unsigned short* Bs,
                                       int rowbase, int quad, int l16, f32x4 (&acc)[8]) {
#pragma unroll
  for (int kk = 0; kk < 4; ++kk) {
    int cb = kk * 4 + quad;
    int row = rowbase + l16;
    bf16x8 a = __builtin_bit_cast(bf16x8, *(const uint4*)&As[row * 128 + ((cb ^ (row & 15)) << 3)]);
    bf16x8 bb[8];
#pragma unroll
    for (int ct = 0; ct < 8; ++ct) {
      int n = ct * 16 + l16;
      bb[ct] = __builtin_bit_cast(bf16x8, *(const uint4*)&Bs[n * 128 + ((cb ^ (n & 15)) << 3)]);
    }
#pragma unroll
    for (int ct = 0; ct < 8; ++ct)
      acc[ct] = __builtin_amdgcn_mfma_f32_16x16x32_bf16(a, bb[ct], acc[ct], 0, 0, 0);
  }
}

// ---------------------------------------------------------------------------
// K1: LN1 -> bf16 tile in LDS -> one 128-col segment of QKV GEMM.
// grid = (3 segs, 192 row-tiles) x 256 thr; 64 rows/block; LDS 48 KB.
// ---------------------------------------------------------------------------
__global__ void __launch_bounds__(256) k1_ln_qkv(const float* __restrict__ x,
                                                 const float* __restrict__ g1,
                                                 const float* __restrict__ b1,
                                                 const unsigned short* __restrict__ wt,
                                                 float* __restrict__ qkv) {
  __shared__ unsigned short As[64 * 128];
  __shared__ unsigned short Bs[128 * 128];
  const int seg = blockIdx.x, row0 = blockIdx.y * 64;
  const int t = threadIdx.x, w = t >> 6, lane = t & 63, quad = lane >> 4, l16 = lane & 15;
  {  // LN: 4 threads per row; wave w covers rows [16w,16w+16) = its MFMA rows
    const int r = t >> 2, c0 = (t & 3) * 32;
    const float* xr = x + (size_t)(row0 + r) * D_ + c0;
    f32x4 xv[8], gv[8], bv[8];
#pragma unroll
    for (int i = 0; i < 8; ++i) {
      xv[i] = *(const f32x4*)(xr + 4 * i);
      gv[i] = *(const f32x4*)(g1 + c0 + 4 * i);
      bv[i] = *(const f32x4*)(b1 + c0 + 4 * i);
    }
    float s = 0.f;
#pragma unroll
    for (int i = 0; i < 8; ++i) s += xv[i][0] + xv[i][1] + xv[i][2] + xv[i][3];
    s += __shfl_xor(s, 1); s += __shfl_xor(s, 2);
    const float mu = s * (1.f / 128.f);
    float sq = 0.f;
#pragma unroll
    for (int i = 0; i < 8; ++i)
#pragma unroll
      for (int j = 0; j < 4; ++j) { float d = xv[i][j] - mu; sq += d * d; }
    sq += __shfl_xor(sq, 1); sq += __shfl_xor(sq, 2);
    const float rstd = rsqrtf(sq * (1.f / 128.f) + 1e-5f);
#pragma unroll
    for (int k = 0; k < 4; ++k) {
      u16x8 pk;
#pragma unroll
      for (int j = 0; j < 8; ++j) {
        int m = k * 8 + j;
        pk[j] = f2bf((xv[m >> 2][m & 3] - mu) * rstd * gv[m >> 2][m & 3] + bv[m >> 2][m & 3]);
      }
      int c = (c0 >> 3) + k;
      *(u16x8*)&As[r * 128 + ((c ^ (r & 15)) << 3)] = pk;
    }
  }
  for (int i = t; i < 2048; i += 256) {  // Bs <- seg's 128x128 weight tile
    int rr = i >> 4, cc = i & 15;
    uint4 vb = *(const uint4*)&wt[(size_t)(seg * 128 + rr) * 128 + cc * 8];
    *(uint4*)&Bs[rr * 128 + ((cc ^ (rr & 15)) << 3)] = vb;
  }
  __syncthreads();
  f32x4 acc[8];
#pragma unroll
  for (int j = 0; j < 8; ++j) acc[j] = f32x4{0.f, 0.f, 0.f, 0.f};
  mfma16(As, Bs, w * 16, quad, l16, acc);
#pragma unroll
  for (int ct = 0; ct < 8; ++ct)
#pragma unroll
    for (int i = 0; i < 4; ++i) {
      int row = row0 + w * 16 + quad * 4 + i;
      int col = seg * 128 + ct * 16 + l16;
      qkv[(size_t)row * 384 + col] = acc[ct][i];
    }
}

// ---------------------------------------------------------------------------
// K2: sparse masked attention. grid = B*S blocks, 128 thr = 8 heads x 16 dims.
// qkv packed [row][384] fp32 (q|k|v). Output bf16.
// ---------------------------------------------------------------------------
__global__ void attn_kernel(const float* __restrict__ qkv, const int* __restrict__ adj,
                            const int* __restrict__ adjcnt, unsigned short* __restrict__ o) {
  int bs = blockIdx.x;
  int s = bs % S_;
  int bbase = bs - s;  // b*S
  int tid = threadIdx.x;
  int h = tid >> 4, d = tid & 15;
  int cnt = adjcnt[s];
  __shared__ int keys[MAXDEG];
  __shared__ float sc[8][MAXDEG];
  for (int j = tid; j < cnt; j += 128) keys[j] = adj[s * MAXDEG + j];
  __syncthreads();
  float qd = qkv[(size_t)bs * 384 + h * 16 + d];
  for (int j = 0; j < cnt; ++j) {
    float kd = qkv[(size_t)(bbase + keys[j]) * 384 + 128 + h * 16 + d];
    float p = qd * kd;
    for (int off = 8; off; off >>= 1) p += __shfl_xor(p, off, 16);
    if (d == 0) sc[h][j] = p * 0.25f;  // 1/sqrt(HD)=0.25
  }
  __syncthreads();
  float mx = -1e30f;
  for (int j = d; j < cnt; j += 16) mx = fmaxf(mx, sc[h][j]);
  for (int off = 8; off; off >>= 1) mx = fmaxf(mx, __shfl_xor(mx, off, 16));
  float sum = 0.f;
  for (int j = d; j < cnt; j += 16) {
    float e = expf(sc[h][j] - mx);
    sc[h][j] = e;
    sum += e;
  }
  for (int off = 8; off; off >>= 1) sum += __shfl_xor(sum, off, 16);
  __syncthreads();
  float acc = 0.f;
  for (int j = 0; j < cnt; ++j)
    acc += sc[h][j] * qkv[(size_t)(bbase + keys[j]) * 384 + 256 + h * 16 + d];
  o[(size_t)bs * D_ + tid] = f2bf(acc / sum);
}

// ---------------------------------------------------------------------------
// K3: o@Wo + x -> LN2*te -> relu(.@W1) -> @W2 -> + residual (+ fc head LAST).
// grid = 192 blocks x 256 thr, 64 rows/block; LDS 64 KB -> 2 blocks/CU.
// x' and acc2 stay in registers (MFMA C-layout); h2/hf round-trip LDS only.
// ---------------------------------------------------------------------------
template <bool LAST>
__global__ void __launch_bounds__(256) k3_rest(
    const unsigned short* __restrict__ ob, const unsigned short* __restrict__ wo,
    const unsigned short* __restrict__ w1, const unsigned short* __restrict__ w2,
    const float* __restrict__ g2, const float* __restrict__ b2,
    const int* __restrict__ tt, const float* __restrict__ table,
    float* __restrict__ x, const float* __restrict__ fcw,
    const float* __restrict__ fcb, float* __restrict__ out) {
  __shared__ unsigned short As[64 * 128];
  __shared__ unsigned short Bs[128 * 128];
  __shared__ unsigned short Cs[64 * 128];
  __shared__ float teS[128], gS[128], bS[128], fS[128];
  const int row0 = blockIdx.x * 64;
  const int t = threadIdx.x, w = t >> 6, lane = t & 63, quad = lane >> 4, l16 = lane & 15;
  const int rowbase = w * 16;
  if (t < 128) {
    int b = row0 / S_;  // 64-row block stays within one batch (1536 % 64 == 0)
    teS[t] = table[tt[b] * D_ + t];
    gS[t] = g2[t];
    bS[t] = b2[t];
    if (LAST) fS[t] = fcw[t];
  }
  // stage As <- o tile (wave-private rows), Bs <- Wo^T (cooperative)
  for (int i = w * 256 + lane; i < w * 256 + 256; i += 64) {
    int rr = i >> 4, cc = i & 15;
    uint4 va = *(const uint4*)&ob[(size_t)(row0 + rr) * D_ + cc * 8];
    *(uint4*)&As[rr * 128 + ((cc ^ (rr & 15)) << 3)] = va;
  }
  for (int i = t; i < 2048; i += 256) {
    int rr = i >> 4, cc = i & 15;
    uint4 vb = *(const uint4*)&wo[(size_t)rr * 128 + cc * 8];
    *(uint4*)&Bs[rr * 128 + ((cc ^ (rr & 15)) << 3)] = vb;
  }
  __syncthreads();
  f32x4 acc1[8];
#pragma unroll
  for (int j = 0; j < 8; ++j) acc1[j] = f32x4{0.f, 0.f, 0.f, 0.f};
  mfma16(As, Bs, rowbase, quad, l16, acc1);
  // x' = x + o@Wo, held in C-layout registers
  f32x4 xp[8];
#pragma unroll
  for (int ct = 0; ct < 8; ++ct)
#pragma unroll
    for (int i = 0; i < 4; ++i) {
      int row = row0 + rowbase + quad * 4 + i;
      int col = ct * 16 + l16;
      xp[ct][i] = x[(size_t)row * D_ + col] + acc1[ct][i];
    }
  // LN2 per row: row (quad,i) spread over 16 lanes (l16) x 8 regs (ct)
  float mu_[4], rs_[4];
#pragma unroll
  for (int i = 0; i < 4; ++i) {
    float s = 0.f;
#pragma unroll
    for (int ct = 0; ct < 8; ++ct) s += xp[ct][i];
    for (int off = 1; off < 16; off <<= 1) s += __shfl_xor(s, off);
    float mu = s * (1.f / 128.f);
    float sq = 0.f;
#pragma unroll
    for (int ct = 0; ct < 8; ++ct) { float d = xp[ct][i] - mu; sq += d * d; }
    for (int off = 1; off < 16; off <<= 1) sq += __shfl_xor(sq, off);
    mu_[i] = mu;
    rs_[i] = rsqrtf(sq * (1.f / 128.f) + 1e-5f);
  }
  __syncthreads();  // everyone done reading As(o)/Bs(Wo)
  // h2 = (LN2(x')*g+b)*te -> bf16 -> As (wave-private rows, A-layout)
#pragma unroll
  for (int ct = 0; ct < 8; ++ct)
#pragma unroll
    for (int i = 0; i < 4; ++i) {
      int rowL = rowbase + quad * 4 + i;
      int col = ct * 16 + l16;
      float h2 = (xp[ct][i] - mu_[i]) * rs_[i] * gS[col] + bS[col];
      h2 *= teS[col];
      As[rowL * 128 + (((col >> 3) ^ (rowL & 15)) << 3) + (col & 7)] = f2bf(h2);
    }
  // FFN: per 128-col chunk c: Cs = relu(h2 @ W1c); acc2 += Cs @ W2c
  f32x4 acc2[8];
#pragma unroll
  for (int j = 0; j < 8; ++j) acc2[j] = f32x4{0.f, 0.f, 0.f, 0.f};
  for (int c = 0; c < 4; ++c) {
    for (int i = t; i < 2048; i += 256) {  // Bs <- W1t rows [c*128, +128)
      int rr = i >> 4, cc = i & 15;
      uint4 vb = *(const uint4*)&w1[(size_t)(c * 128 + rr) * 128 + cc * 8];
      *(uint4*)&Bs[rr * 128 + ((cc ^ (rr & 15)) << 3)] = vb;
    }
    __syncthreads();
    f32x4 accF[8];
#pragma unroll
    for (int j = 0; j < 8; ++j) accF[j] = f32x4{0.f, 0.f, 0.f, 0.f};
    mfma16(As, Bs, rowbase, quad, l16, accF);
#pragma unroll
    for (int ct = 0; ct < 8; ++ct)
#pragma unroll
      for (int i = 0; i < 4; ++i) {
        int rowL = rowbase + quad * 4 + i;
        int col = ct * 16 + l16;
        Cs[rowL * 128 + (((col >> 3) ^ (rowL & 15)) << 3) + (col & 7)] =
            f2bf(fmaxf(accF[ct][i], 0.f));
      }
    __syncthreads();  // all waves done reading Bs(W1) + Cs writes drained
    for (int i = t; i < 2048; i += 256) {  // Bs <- W2t k-chunk c
      int rr = i >> 4, cc = i & 15;
      uint4 vb = *(const uint4*)&w2[(size_t)rr * 512 + c * 128 + cc * 8];
      *(uint4*)&Bs[rr * 128 + ((cc ^ (rr & 15)) << 3)] = vb;
    }
    __syncthreads();
    mfma16(Cs, Bs, rowbase, quad, l16, acc2);
    __syncthreads();  // before next c overwrites Bs
  }
  // epilogue: x'' = x' + ffn
  if (!LAST) {
#pragma unroll
    for (int ct = 0; ct < 8; ++ct)
#pragma unroll
      for (int i = 0; i < 4; ++i) {
        int row = row0 + rowbase + quad * 4 + i;
        int col = ct * 16 + l16;
        x[(size_t)row * D_ + col] = xp[ct][i] + acc2[ct][i];
      }
  } else {
    float pr[4] = {0.f, 0.f, 0.f, 0.f};
#pragma unroll
    for (int ct = 0; ct < 8; ++ct)
#pragma unroll
      for (int i = 0; i < 4; ++i)
        pr[i] += (xp[ct][i] + acc2[ct][i]) * fS[ct * 16 + l16];
#pragma unroll
    for (int i = 0; i < 4; ++i) {
      float s = pr[i];
      for (int off = 1; off < 16; off <<= 1) s += __shfl_xor(s, off);
      if (l16 == 0) out[row0 + rowbase + quad * 4 + i] = s + fcb[0];
    }
  }
}

// ---------------------------------------------------------------------------
extern "C" void kernel_launch(void* const* d_in, const int* in_sizes, int n_in,
                              void* d_out, int out_size, void* d_ws, size_t ws_size,
                              hipStream_t stream) {
  const float* r_t       = (const float*)d_in[0];
  const int*   t         = (const int*)d_in[1];
  const int*   pcm       = (const int*)d_in[2];
  // d_in[3] = mask: unused, adjacency derived from pcm (identical support)
  const float* src_embed = (const float*)d_in[4];
  const float* time_tab  = (const float*)d_in[5];
  const float* Wq = (const float*)d_in[6];
  const float* Wk = (const float*)d_in[7];
  const float* Wv = (const float*)d_in[8];
  const float* Wo = (const float*)d_in[9];
  const float* W1 = (const float*)d_in[10];
  const float* W2 = (const float*)d_in[11];
  const float* g1 = (const float*)d_in[12];
  const float* b1 = (const float*)d_in[13];
  const float* g2 = (const float*)d_in[14];
  const float* b2 = (const float*)d_in[15];
  const float* fc_w = (const float*)d_in[16];
  const float* fc_b = (const float*)d_in[17];
  float* out = (float*)d_out;

  char* ws = (char*)d_ws;
  size_t off = 0;
  auto alloc = [&](size_t bytes) -> void* {
    void* p = ws + off;
    off = (off + bytes + 255) & ~(size_t)255;
    return p;
  };
  float*          x    = (float*)alloc((size_t)ROWS * D_ * 4);
  float*          qkv  = (float*)alloc((size_t)ROWS * 384 * 4);
  unsigned short* ob   = (unsigned short*)alloc((size_t)ROWS * D_ * 2);
  int*            adj  = (int*)alloc((size_t)S_ * MAXDEG * 4);
  int*            adjc = (int*)alloc((size_t)S_ * 4);
  unsigned short* wbf  = (unsigned short*)alloc((size_t)L_ * WLAYER * 2);

  adj_kernel<<<S_, 64, 0, stream>>>(pcm, adj, adjc);
  wconv_kernel<<<(L_ * WLAYER + 255) / 256, 256, 0, stream>>>(Wq, Wk, Wv, Wo, W1, W2, wbf);
  xinit_kernel<<<ROWS, 128, 0, stream>>>(r_t, adj, adjc, src_embed, t, time_tab, x);

  for (int l = 0; l < L_; ++l) {
    const unsigned short* wl = wbf + (size_t)l * WLAYER;
    k1_ln_qkv<<<dim3(3, ROWS / 64), 256, 0, stream>>>(x, g1 + l * D_, b1 + l * D_, wl, qkv);
    attn_kernel<<<ROWS, 128, 0, stream>>>(qkv, adj, adjc, ob);
    if (l < L_ - 1) {
      k3_rest<false><<<ROWS / 64, 256, 0, stream>>>(
          ob, wl + WSEG_QKV, wl + WSEG_QKV + WSEG_O, wl + WSEG_QKV + WSEG_O + WSEG_1,
          g2 + l * D_, b2 + l * D_, t, time_tab, x, nullptr, nullptr, nullptr);
    } else {
      k3_rest<true><<<ROWS / 64, 256, 0, stream>>>(
          ob, wl + WSEG_QKV, wl + WSEG_QKV + WSEG_O, wl + WSEG_QKV + WSEG_O + WSEG_1,
          g2 + l * D_, b2 + l * D_, t, time_tab, x, fc_w, fc_b, out);
    }
  }
}